// Round 1
// baseline (4048.763 us; speedup 1.0000x reference)
//
#include <hip/hip_runtime.h>
#include <hip/hip_fp16.h>
#include <cstdio>

// EmbeddingCellLSTM: B=32, S=2048, IN=64, EMB=32, H=256, 4H=1024
// Design:
//  k1 pack_kernel : W_hh fp32 -> fp16 packed into per-thread register/LDS layouts (ws)
//  k2 zx_kernel   : zx[b][s][j*4+g] = (concat(x,emb) @ W_ih^T + b) as fp16 (ws)
//  k3 lstm_kernel : 32 blocks (1 per batch) x 1024 threads; thread (j,p) owns the 4
//                   gate rows of hidden unit j over k in [64p,64p+64). 48 k/row in
//                   96 VGPRs (fp16 pairs), 16 k/row in 128KB dynamic LDS. Per step:
//                   dot2 MACs -> DPP quad reduce -> activations -> DPP quad bcast ->
//                   c/h update (replicated per quad), 1 __syncthreads()/step,
//                   double-buffered 256-entry fp16 h in LDS.

#define ZX_BYTES   (134217728u)            // 32*2048*1024*2
#define WREG_OFF   (134217728u)
#define WREG_BYTES (393216u)               // 96*1024*4
#define WL_OFF     (134217728u + 393216u)
#define WL_BYTES   (131072u)               // 8*1024*16
#define LSTM_LDS   (132096u)               // 131072 WL + 2*512 hbuf

typedef _Float16 h2_t __attribute__((ext_vector_type(2)));

static __device__ __forceinline__ unsigned short f16bits(float v) {
  _Float16 h = (_Float16)v;
  return __builtin_bit_cast(unsigned short, h);
}
static __device__ __forceinline__ unsigned int pack2(float a, float b) {
  return (unsigned int)f16bits(a) | ((unsigned int)f16bits(b) << 16);
}
static __device__ __forceinline__ float dot2f(unsigned int w, unsigned int h, float acc) {
#if __has_builtin(__builtin_amdgcn_fdot2)
  return __builtin_amdgcn_fdot2(__builtin_bit_cast(h2_t, w), __builtin_bit_cast(h2_t, h), acc, false);
#else
  h2_t wv = __builtin_bit_cast(h2_t, w), hv = __builtin_bit_cast(h2_t, h);
  return acc + (float)wv[0] * (float)hv[0] + (float)wv[1] * (float)hv[1];
#endif
}
template <int CTRL>
static __device__ __forceinline__ float qmov(float x) {
  int v = __builtin_amdgcn_update_dpp(0, __builtin_bit_cast(int, x), CTRL, 0xF, 0xF, true);
  return __builtin_bit_cast(float, v);
}
static __device__ __forceinline__ float quad_sum(float x) {
  x += qmov<0xB1>(x);  // quad_perm(1,0,3,2)
  x += qmov<0x4E>(x);  // quad_perm(2,3,0,1)
  return x;
}

// ---------------- k1: pack W_hh into fp16 register/LDS layouts ----------------
__global__ __launch_bounds__(1024) void pack_kernel(const float* __restrict__ Whh,
                                                    unsigned int* __restrict__ wreg,
                                                    unsigned int* __restrict__ wl) {
  int slot = blockIdx.x;          // 0..127 : 96 reg slots + 32 LDS slots
  int t = threadIdx.x;            // 0..1023
  int j = t >> 2, p = t & 3;
  int g, ksub, q;
  bool isreg = slot < 96;
  if (isreg) { g = slot / 24; int rr = slot - g * 24; ksub = rr >> 2; q = rr & 3; }
  else       { int ls = slot - 96; g = ls >> 3; ksub = 6 + ((ls >> 2) & 1); q = ls & 3; }
  int row = g * 256 + j;
  int k = p * 64 + ksub * 8 + q * 2;
  float w0 = Whh[row * 256 + k];
  float w1 = Whh[row * 256 + k + 1];
  unsigned int pk = pack2(w0, w1);
  if (isreg) {
    wreg[slot * 1024 + t] = pk;
  } else {
    int ls = slot - 96;
    int sl = ls >> 2;             // g*2 + (ksub-6)
    wl[sl * 4096 + t * 4 + q] = pk;
  }
}

// ---------------- k2: zx = concat(x,emb) @ W_ih^T + b  (fp16, [b][s][j*4+g]) ----------------
__global__ __launch_bounds__(256) void zx_kernel(const float* __restrict__ x,
                                                 const float* __restrict__ emb,
                                                 const float* __restrict__ Wih,
                                                 const float* __restrict__ bias,
                                                 unsigned short* __restrict__ zx) {
  __shared__ __align__(16) float XeT[96][68];
  __shared__ __align__(16) float WT[96][68];
  int mt = blockIdx.x, nt = blockIdx.y;     // 1024 x 16
  int m0 = mt * 64, n0 = nt * 64;
  int tid = threadIdx.x;
  for (int idx = tid; idx < 6144; idx += 256) {
    int r = idx / 96, k = idx - r * 96;
    size_t m = (size_t)(m0 + r);
    float v = (k < 64) ? x[m * 64 + k] : emb[m * 32 + (k - 64)];
    XeT[k][r] = v;
  }
  for (int idx = tid; idx < 6144; idx += 256) {
    int c = idx / 96, k = idx - c * 96;
    WT[k][c] = Wih[(size_t)(n0 + c) * 96 + k];
  }
  __syncthreads();
  int ty = tid >> 4, tx = tid & 15;
  int r0 = ty * 4, c0 = tx * 4;
  float acc[4][4] = {};
  for (int k = 0; k < 96; k++) {
    float4 a = *(const float4*)&XeT[k][r0];
    float4 w = *(const float4*)&WT[k][c0];
    float av[4] = {a.x, a.y, a.z, a.w};
    float wv[4] = {w.x, w.y, w.z, w.w};
#pragma unroll
    for (int i = 0; i < 4; i++)
#pragma unroll
      for (int jj = 0; jj < 4; jj++) acc[i][jj] += av[i] * wv[jj];
  }
  int g = n0 >> 8;   // whole 64-col tile lies in one gate
#pragma unroll
  for (int i = 0; i < 4; i++) {
    size_t m = (size_t)(m0 + r0 + i);
#pragma unroll
    for (int jj = 0; jj < 4; jj++) {
      int col = n0 + c0 + jj;
      int ju = col & 255;
      float v = acc[i][jj] + bias[col];
      zx[m * 1024 + (size_t)(ju * 4 + g)] = f16bits(v);
    }
  }
}

// ---------------- k3: persistent per-batch LSTM ----------------
__global__ __launch_bounds__(1024) void lstm_kernel(const unsigned short* __restrict__ zx,
                                                    const unsigned int* __restrict__ wreg_src,
                                                    const uint4* __restrict__ wl_src,
                                                    float* __restrict__ out) {
  extern __shared__ char smem[];
  uint4* WLds = (uint4*)smem;                       // 131072 B
  int t = threadIdx.x;
  int b = blockIdx.x;
  int j = t >> 2, p = t & 3;

  // stage LDS-resident weights (coalesced: lane-stride 16B)
#pragma unroll
  for (int sl = 0; sl < 8; sl++) WLds[sl * 1024 + t] = wl_src[sl * 1024 + t];
  // zero both h buffers (2 x 256 fp16 = 512 ushorts)
  if (t < 512) ((unsigned short*)(smem + 131072))[t] = 0;

  // register-resident weights: 96 u32 = 192 fp16 (4 gates x 48 k-values)
  unsigned int wr[96];
#pragma unroll
  for (int r = 0; r < 96; r++) wr[r] = wreg_src[r * 1024 + t];
  __syncthreads();

  const unsigned short* zxb = zx + (size_t)b * (2048u * 1024u);
  float* outb = out + (size_t)b * (2048u * 256u);
  float c_cur = 0.f, h_cur = 0.f;
  bool isg2 = (p == 2);
  const float sc = isg2 ? 2.88539008f : 1.44269504f;

  for (int s = 0; s < 2048; s++) {
    const char* hbc = smem + 131072 + ((s & 1) ? 512 : 0);
    char* hbn = (char*)smem + 131072 + ((s & 1) ? 0 : 512);
    unsigned short zxu = zxb[(size_t)s * 1024 + t];   // independent load, hidden by compute

    float acc[4] = {0.f, 0.f, 0.f, 0.f};
    const char* hbase = hbc + p * 128;
#pragma unroll
    for (int ks = 0; ks < 6; ks++) {
      uint4 hv = *(const uint4*)(hbase + ks * 16);
      unsigned int hh[4] = {hv.x, hv.y, hv.z, hv.w};
#pragma unroll
      for (int g = 0; g < 4; g++)
#pragma unroll
        for (int q = 0; q < 4; q++) acc[g] = dot2f(wr[g * 24 + ks * 4 + q], hh[q], acc[g]);
    }
#pragma unroll
    for (int ks = 0; ks < 2; ks++) {
      uint4 hv = *(const uint4*)(hbase + (6 + ks) * 16);
      unsigned int hh[4] = {hv.x, hv.y, hv.z, hv.w};
#pragma unroll
      for (int g = 0; g < 4; g++) {
        uint4 wv = WLds[(g * 2 + ks) * 1024 + t];
        unsigned int ww[4] = {wv.x, wv.y, wv.z, wv.w};
#pragma unroll
        for (int q = 0; q < 4; q++) acc[g] = dot2f(ww[q], hh[q], acc[g]);
      }
    }
    // quad (p=0..3) k-reduction, all lanes get full sums
    float z0 = quad_sum(acc[0]);
    float z1 = quad_sum(acc[1]);
    float z2 = quad_sum(acc[2]);
    float z3 = quad_sum(acc[3]);
    float zm = (p & 2) ? ((p & 1) ? z3 : z2) : ((p & 1) ? z1 : z0);
    zm += (float)__builtin_bit_cast(_Float16, zxu);
    // lane p applies activation for gate p: i,f,o -> sigmoid ; g -> tanh
    float e = __builtin_amdgcn_exp2f(-sc * zm);
    float r = __builtin_amdgcn_rcpf(1.f + e);
    float a = isg2 ? (2.f * r - 1.f) : r;
    // broadcast the 4 activated gates within the quad (VALU pipe, no LDS)
    float ai = qmov<0x00>(a);
    float af = qmov<0x55>(a);
    float ag = qmov<0xAA>(a);
    float ao = qmov<0xFF>(a);
    float c = af * c_cur + ai * ag;
    float e2 = __builtin_amdgcn_exp2f(-2.88539008f * c);
    float th = 2.f * __builtin_amdgcn_rcpf(1.f + e2) - 1.f;
    float h = ao * th;
    c_cur = c;
    h_cur = h;
    if (p == 0) {
      ((unsigned short*)hbn)[j] = f16bits(h);
      outb[s * 256 + j] = h;
    }
    __syncthreads();
  }
  if (p == 0) {
    out[16777216u + (size_t)b * 256 + j] = h_cur;              // final h
    out[16777216u + 8192u + (size_t)b * 256 + j] = c_cur;      // final c
  }
}

extern "C" void kernel_launch(void* const* d_in, const int* in_sizes, int n_in,
                              void* d_out, int out_size, void* d_ws, size_t ws_size,
                              hipStream_t stream) {
  const float* x = (const float*)d_in[0];
  const float* emb = (const float*)d_in[1];
  const float* W_ih = (const float*)d_in[2];
  const float* W_hh = (const float*)d_in[3];
  const float* bias = (const float*)d_in[4];
  float* out = (float*)d_out;
  char* ws = (char*)d_ws;

  unsigned short* zx = (unsigned short*)ws;
  unsigned int* wreg = (unsigned int*)(ws + WREG_OFF);
  unsigned int* wl = (unsigned int*)(ws + WL_OFF);

  size_t need = (size_t)WL_OFF + WL_BYTES;
  if (ws_size < need) {
    fprintf(stderr, "kernel_launch: ws too small: %zu < %zu\n", ws_size, need);
  }

  (void)hipFuncSetAttribute((const void*)lstm_kernel,
                            hipFuncAttributeMaxDynamicSharedMemorySize, LSTM_LDS);

  pack_kernel<<<dim3(128), dim3(1024), 0, stream>>>(W_hh, wreg, wl);
  zx_kernel<<<dim3(1024, 16), dim3(256), 0, stream>>>(x, emb, W_ih, bias, zx);
  lstm_kernel<<<dim3(32), dim3(1024), LSTM_LDS, stream>>>(zx, wreg, (const uint4*)wl, out);
}

// Round 2
// 3994.889 us; speedup vs baseline: 1.0135x; 1.0135x over previous
//
#include <hip/hip_runtime.h>
#include <hip/hip_fp16.h>
#include <cstdio>

// EmbeddingCellLSTM: B=32, S=2048, IN=64, EMB=32, H=256, 4H=1024
//  k1 pack_kernel : W_hh fp32 -> fp16 packed per-thread reg/LDS layouts (ws)
//  k2 zx_kernel   : zx[b][s][j*4+g] = (concat(x,emb) @ W_ih^T + b) fp16 (ws)
//  k3 lstm_kernel : 32 blocks (1/batch) x 1024 thr; thread (j,p) owns 4 gate
//                   rows of unit j over k in [64p,64p+64). 48 k/row in 96 VGPRs,
//                   16 k/row in 128KB LDS. h kept in LDS as 4 bank-staggered
//                   copies (stride 544B) -> conflict-free broadcast reads.
//                   1 __syncthreads()/step, double-buffered h.

#define WREG_OFF   (134217728u)
#define WL_OFF     (134217728u + 393216u)
#define WL_BYTES   (131072u)
#define HB_OFF     (131072u)               // within LDS
#define LSTM_LDS   (131072u + 4352u)       // WL + 2 bufs x 4 copies x 544B

typedef _Float16 h2_t __attribute__((ext_vector_type(2)));

static __device__ __forceinline__ unsigned short f16bits(float v) {
  _Float16 h = (_Float16)v;
  return __builtin_bit_cast(unsigned short, h);
}
static __device__ __forceinline__ unsigned int pack2(float a, float b) {
  return (unsigned int)f16bits(a) | ((unsigned int)f16bits(b) << 16);
}
static __device__ __forceinline__ float dot2f(unsigned int w, unsigned int h, float acc) {
#if __has_builtin(__builtin_amdgcn_fdot2)
  return __builtin_amdgcn_fdot2(__builtin_bit_cast(h2_t, w), __builtin_bit_cast(h2_t, h), acc, false);
#else
  h2_t wv = __builtin_bit_cast(h2_t, w), hv = __builtin_bit_cast(h2_t, h);
  return acc + (float)wv[0] * (float)hv[0] + (float)wv[1] * (float)hv[1];
#endif
}
template <int CTRL>
static __device__ __forceinline__ float qmov(float x) {
  int v = __builtin_amdgcn_update_dpp(0, __builtin_bit_cast(int, x), CTRL, 0xF, 0xF, true);
  return __builtin_bit_cast(float, v);
}

// ---------------- k1: pack W_hh into fp16 register/LDS layouts ----------------
__global__ __launch_bounds__(1024) void pack_kernel(const float* __restrict__ Whh,
                                                    unsigned int* __restrict__ wreg,
                                                    unsigned int* __restrict__ wl) {
  int slot = blockIdx.x;          // 0..127 : 96 reg slots + 32 LDS slots
  int t = threadIdx.x;
  int j = t >> 2, p = t & 3;
  int g, ksub, q;
  bool isreg = slot < 96;
  if (isreg) { g = slot / 24; int rr = slot - g * 24; ksub = rr >> 2; q = rr & 3; }
  else       { int ls = slot - 96; g = ls >> 3; ksub = 6 + ((ls >> 2) & 1); q = ls & 3; }
  int row = g * 256 + j;
  int k = p * 64 + ksub * 8 + q * 2;
  unsigned int pk = pack2(Whh[row * 256 + k], Whh[row * 256 + k + 1]);
  if (isreg) {
    wreg[slot * 1024 + t] = pk;
  } else {
    int ls = slot - 96;
    int sl = ls >> 2;             // g*2 + (ksub-6)
    wl[sl * 4096 + t * 4 + q] = pk;
  }
}

// ---------------- k2: zx = concat(x,emb) @ W_ih^T + b  (fp16, [b][s][j*4+g]) ----------------
__global__ __launch_bounds__(256) void zx_kernel(const float* __restrict__ x,
                                                 const float* __restrict__ emb,
                                                 const float* __restrict__ Wih,
                                                 const float* __restrict__ bias,
                                                 unsigned short* __restrict__ zx) {
  __shared__ __align__(16) float XeT[96][68];
  __shared__ __align__(16) float WT[96][68];
  int mt = blockIdx.x, nt = blockIdx.y;     // 1024 x 16
  int m0 = mt * 64, n0 = nt * 64;
  int tid = threadIdx.x;
  for (int idx = tid; idx < 6144; idx += 256) {
    int r = idx / 96, k = idx - r * 96;
    size_t m = (size_t)(m0 + r);
    float v = (k < 64) ? x[m * 64 + k] : emb[m * 32 + (k - 64)];
    XeT[k][r] = v;
  }
  for (int idx = tid; idx < 6144; idx += 256) {
    int c = idx / 96, k = idx - c * 96;
    WT[k][c] = Wih[(size_t)(n0 + c) * 96 + k];
  }
  __syncthreads();
  int ty = tid >> 4, tx = tid & 15;
  int r0 = ty * 4, c0 = tx * 4;
  float acc[4][4] = {};
  for (int k = 0; k < 96; k++) {
    float4 a = *(const float4*)&XeT[k][r0];
    float4 w = *(const float4*)&WT[k][c0];
    float av[4] = {a.x, a.y, a.z, a.w};
    float wv[4] = {w.x, w.y, w.z, w.w};
#pragma unroll
    for (int i = 0; i < 4; i++)
#pragma unroll
      for (int jj = 0; jj < 4; jj++) acc[i][jj] += av[i] * wv[jj];
  }
  int g = n0 >> 8;
#pragma unroll
  for (int i = 0; i < 4; i++) {
    size_t m = (size_t)(m0 + r0 + i);
#pragma unroll
    for (int jj = 0; jj < 4; jj++) {
      int col = n0 + c0 + jj;
      int ju = col & 255;
      float v = acc[i][jj] + bias[col];
      zx[m * 1024 + (size_t)(ju * 4 + g)] = f16bits(v);
    }
  }
}

// ---------------- k3: persistent per-batch LSTM ----------------
__global__ __launch_bounds__(1024, 4) void lstm_kernel(const unsigned short* __restrict__ zx,
                                                       const unsigned int* __restrict__ wreg_src,
                                                       const uint4* __restrict__ wl_src,
                                                       float* __restrict__ out) {
  extern __shared__ char smem[];
  uint4* WLds = (uint4*)smem;                       // 131072 B
  const int t = threadIdx.x;
  const int b = blockIdx.x;
  const int j = t >> 2, p = t & 3;

  // stage LDS-resident weights (consecutive b128 -> conflict-free)
#pragma unroll
  for (int sl = 0; sl < 8; sl++) WLds[sl * 1024 + t] = wl_src[sl * 1024 + t];
  // zero h region: 2 bufs x 4 copies x 544 B = 4352 B = 1088 u32
  ((unsigned int*)(smem + HB_OFF))[t] = 0;
  if (t < 64) ((unsigned int*)(smem + HB_OFF))[1024 + t] = 0;

  // register-resident weights: 96 u32 = 4 gates x 48 k (fp16 pairs)
  unsigned int wr[96];
#pragma unroll
  for (int r = 0; r < 96; r++) wr[r] = wreg_src[r * 1024 + t];
  __syncthreads();

  const unsigned short* zp = zx + (size_t)b * (2048u * 1024u) + t;
  float* op = out + (size_t)b * (2048u * 256u) + j;
  float c_cur = 0.f, h_cur = 0.f;
  const bool b0 = (p & 1) != 0;
  const bool b1 = (p & 2) != 0;
  const bool isg2 = (p == 2);
  const bool isp0 = (p == 0);
  const float sc = isg2 ? 2.88539008f : 1.44269504f;
  // h copy p, my k-slice base: HB + p*544 (copy) + p*128 (slice) = HB + p*672
  const char* hr0 = smem + HB_OFF + p * 672;
  char* hw0 = smem + HB_OFF + p * 544 + j * 2;

  for (int s = 0; s < 2048; s++) {
    const int rdoff = (s & 1) ? 2176 : 0;
    const char* hb = hr0 + rdoff;
    unsigned short zxu = *zp;                        // hidden by compute
    zp += 1024;

    float acc[4] = {0.f, 0.f, 0.f, 0.f};
#pragma unroll
    for (int ks = 0; ks < 6; ks++) {
      uint4 hv = *(const uint4*)(hb + ks * 16);
      unsigned int hh[4] = {hv.x, hv.y, hv.z, hv.w};
#pragma unroll
      for (int g = 0; g < 4; g++)
#pragma unroll
        for (int q = 0; q < 4; q++) acc[g] = dot2f(wr[g * 24 + ks * 4 + q], hh[q], acc[g]);
    }
#pragma unroll
    for (int ks = 0; ks < 2; ks++) {
      uint4 hv = *(const uint4*)(hb + (6 + ks) * 16);
      unsigned int hh[4] = {hv.x, hv.y, hv.z, hv.w};
#pragma unroll
      for (int g = 0; g < 4; g++) {
        uint4 wv = WLds[(g * 2 + ks) * 1024 + t];
        unsigned int ww[4] = {wv.x, wv.y, wv.z, wv.w};
#pragma unroll
        for (int q = 0; q < 4; q++) acc[g] = dot2f(ww[q], hh[q], acc[g]);
      }
    }
    // quad reduce-scatter: lane p ends with z for gate p
    float sLo = b0 ? acc[0] : acc[1];
    float sHi = b0 ? acc[2] : acc[3];
    float kLo = b0 ? acc[1] : acc[0];
    float kHi = b0 ? acc[3] : acc[2];
    float aLo = kLo + qmov<0xB1>(sLo);   // xor 1
    float aHi = kHi + qmov<0xB1>(sHi);
    float sB = b1 ? aLo : aHi;
    float kB = b1 ? aHi : aLo;
    float z = kB + qmov<0x4E>(sB);       // xor 2
    z += (float)__builtin_bit_cast(_Float16, zxu);
    // activation: gate 2 -> tanh, else sigmoid
    float e = __builtin_amdgcn_exp2f(-sc * z);
    float r = __builtin_amdgcn_rcpf(1.f + e);
    float a = isg2 ? (2.f * r - 1.f) : r;
    // broadcast 4 activated gates within quad
    float ai = qmov<0x00>(a);
    float af = qmov<0x55>(a);
    float ag = qmov<0xAA>(a);
    float ao = qmov<0xFF>(a);
    float c = af * c_cur + ai * ag;
    float e2 = __builtin_amdgcn_exp2f(-2.88539008f * c);
    float th = 2.f * __builtin_amdgcn_rcpf(1.f + e2) - 1.f;
    float h = ao * th;
    c_cur = c;
    h_cur = h;
    // every lane writes its copy p (2 lanes/bank -> free)
    *(unsigned short*)(hw0 + (2176 - rdoff)) = f16bits(h);
    if (isp0) *op = h;
    op += 256;
    __syncthreads();
  }
  if (isp0) {
    out[16777216u + (size_t)b * 256 + j] = h_cur;              // final h
    out[16777216u + 8192u + (size_t)b * 256 + j] = c_cur;      // final c
  }
}

extern "C" void kernel_launch(void* const* d_in, const int* in_sizes, int n_in,
                              void* d_out, int out_size, void* d_ws, size_t ws_size,
                              hipStream_t stream) {
  const float* x = (const float*)d_in[0];
  const float* emb = (const float*)d_in[1];
  const float* W_ih = (const float*)d_in[2];
  const float* W_hh = (const float*)d_in[3];
  const float* bias = (const float*)d_in[4];
  float* out = (float*)d_out;
  char* ws = (char*)d_ws;

  unsigned short* zx = (unsigned short*)ws;
  unsigned int* wreg = (unsigned int*)(ws + WREG_OFF);
  unsigned int* wl = (unsigned int*)(ws + WL_OFF);

  size_t need = (size_t)WL_OFF + WL_BYTES;
  if (ws_size < need) {
    fprintf(stderr, "kernel_launch: ws too small: %zu < %zu\n", ws_size, need);
  }

  (void)hipFuncSetAttribute((const void*)lstm_kernel,
                            hipFuncAttributeMaxDynamicSharedMemorySize, LSTM_LDS);

  pack_kernel<<<dim3(128), dim3(1024), 0, stream>>>(W_hh, wreg, wl);
  zx_kernel<<<dim3(1024, 16), dim3(256), 0, stream>>>(x, emb, W_ih, bias, zx);
  lstm_kernel<<<dim3(32), dim3(1024), LSTM_LDS, stream>>>(zx, wreg, (const uint4*)wl, out);
}